// Round 12
// baseline (181.101 us; speedup 1.0000x reference)
//
#include <hip/hip_runtime.h>
#include <hip/hip_bf16.h>
#include <math.h>

typedef unsigned short u16;

// ---- ws layout (float/int offsets), FB = 524288 ----
// [0, 262144)        : PO[b][o][g] fp32
// [262144, 524288)   : Y[b][i][g] fp32
// FB+1280 .. +1288   : V fp32
// FB+1288 .. +1800   : hn fp32
// FB+1800 .. +2312   : cn fp32
// FB+2320 .. +4368   : C1PO[b][o]
// FB+4368 .. +6416   : C2[b][i]
// FB+26896.. +27920  : S[b][g]
// FB+27920.. +27928  : C1S[b]
// FB+28000           : barrier flag (int)
// FB+28001           : barrier counter (int)
#define FB     524288
#define SOFF   26896
#define C1S    27920
#define BFLAG  (FB + 28000)
#define BCNT   (FB + 28001)
#define MAGIC  0x5A17C0DE
#define NBLK   264

__device__ __forceinline__ u16 f2b(float x) { __hip_bfloat16 b = __float2bfloat16(x); return *(u16*)&b; }
__device__ __forceinline__ void cvt8(const uint4 u, float* f) {
    f[0] = __uint_as_float(u.x << 16); f[1] = __uint_as_float(u.x & 0xFFFF0000u);
    f[2] = __uint_as_float(u.y << 16); f[3] = __uint_as_float(u.y & 0xFFFF0000u);
    f[4] = __uint_as_float(u.z << 16); f[5] = __uint_as_float(u.z & 0xFFFF0000u);
    f[6] = __uint_as_float(u.w << 16); f[7] = __uint_as_float(u.w & 0xFFFF0000u);
}
__device__ __forceinline__ float dot4(const float4 a, const float4 b) {
    return a.x*b.x + a.y*b.y + a.z*b.z + a.w*b.w;
}
__device__ __forceinline__ int aload(int* p) {
    return __hip_atomic_load(p, __ATOMIC_ACQUIRE, __HIP_MEMORY_SCOPE_AGENT);
}

// ============================================================================
// k_all (grid 264 x 256, 64000 B LDS -> 2 blocks/CU -> all 264 co-resident):
// Phase 1: blocks 0..255 PO/Y tiles (+C1PO/C2); blocks 256..263 LSTM/V/S/C1S.
// Manual device barrier (flag/magic + counter, poison-safe, timeout-capped).
// Phase 2: A-combine, 512 units striped over 264 blocks; block 0 emits V/hn/cn.
// ============================================================================
__global__ __launch_bounds__(256) void k_all(
    const float* __restrict__ ope, const float* __restrict__ ins,
    const float* __restrict__ hin, const float* __restrict__ cin,
    const float* __restrict__ W_ih, const float* __restrict__ W_hh,
    const float* __restrict__ b_ih, const float* __restrict__ b_hh,
    const float* __restrict__ Wv0, const float* __restrict__ bv0,
    const float* __restrict__ Wv1, const float* __restrict__ bv1,
    const float* __restrict__ Wv2, const float* __restrict__ bv2,
    const float* __restrict__ Wa0, const float* __restrict__ ba0,
    const float* __restrict__ Wa1, const float* __restrict__ ba1,
    const float* __restrict__ Wa2, const float* __restrict__ ba2,
    float* __restrict__ ws, float* __restrict__ out)
{
    __shared__ __align__(16) u16 Wa1s[128*136];
    __shared__ __align__(16) u16 Wsel[128*72];
    __shared__ __align__(16) u16 inrows[16*72];
    __shared__ __align__(16) float P[16*132];
    const int t = threadIdx.x;
    int* wsi = (int*)ws;

    // barrier init (block 0, before any work)
    if (blockIdx.x == 0 && t == 0) {
        __hip_atomic_store(&wsi[BCNT], 0, __ATOMIC_RELAXED, __HIP_MEMORY_SCOPE_AGENT);
        __hip_atomic_store(&wsi[BFLAG], MAGIC, __ATOMIC_RELEASE, __HIP_MEMORY_SCOPE_AGENT);
    }

    // ======================= PHASE 1 =======================
    if (blockIdx.x < 256) {
        const int b = blockIdx.x >> 5;
        const int r0 = (blockIdx.x & 31) * 16;
        const int side = (r0 >= 256) ? 1 : 0;

        #pragma unroll
        for (int k = 0; k < 16; ++k) {
            const int e4 = t + k*256;
            const int g = e4 >> 5, hq = (e4 & 31) * 4;
            const float4 w = *(const float4*)(Wa1 + g*128 + hq);
            ushort4 u; u.x = f2b(w.x); u.y = f2b(w.y); u.z = f2b(w.z); u.w = f2b(w.w);
            *(ushort4*)&Wa1s[g*136 + hq] = u;
        }
        #pragma unroll
        for (int k = 0; k < 8; ++k) {
            const int e4 = t + k*256;
            const int h = e4 >> 4, dq = (e4 & 15) * 4;
            const float4 w = *(const float4*)(Wa0 + h*192 + 64 + side*64 + dq);
            ushort4 u; u.x = f2b(w.x); u.y = f2b(w.y); u.z = f2b(w.z); u.w = f2b(w.w);
            *(ushort4*)&Wsel[h*72 + dq] = u;
        }
        {
            const int r = t >> 4, dq = (t & 15) * 4;
            const float* src = side
                ? (ins + b*16384 + (r0 - 256 + r)*64 + dq)
                : (ope + b*16512 + (1 + r0 + r)*64 + dq);
            const float4 w = *(const float4*)src;
            ushort4 u; u.x = f2b(w.x); u.y = f2b(w.y); u.z = f2b(w.z); u.w = f2b(w.w);
            *(ushort4*)&inrows[r*72 + dq] = u;
        }
        __syncthreads();

        const int r = t >> 4;
        const int q = t & 15;

        {
            float acc[8] = {0.f,0.f,0.f,0.f,0.f,0.f,0.f,0.f};
            #pragma unroll
            for (int d8 = 0; d8 < 64; d8 += 8) {
                float iv[8];
                cvt8(*(const uint4*)&inrows[r*72 + d8], iv);
                #pragma unroll
                for (int k = 0; k < 8; ++k) {
                    float wv[8];
                    cvt8(*(const uint4*)&Wsel[(q + 16*k)*72 + d8], wv);
                    #pragma unroll
                    for (int j = 0; j < 8; ++j) acc[k] += wv[j] * iv[j];
                }
            }
            #pragma unroll
            for (int k = 0; k < 8; ++k) P[r*132 + q + 16*k] = acc[k];
        }
        __syncthreads();

        {
            float acc[8] = {0.f,0.f,0.f,0.f,0.f,0.f,0.f,0.f};
            #pragma unroll
            for (int h8 = 0; h8 < 128; h8 += 8) {
                const float4 p0 = *(const float4*)&P[r*132 + h8];
                const float4 p1 = *(const float4*)&P[r*132 + h8 + 4];
                #pragma unroll
                for (int k = 0; k < 8; ++k) {
                    float wv[8];
                    cvt8(*(const uint4*)&Wa1s[(q + 16*k)*136 + h8], wv);
                    float a = acc[k];
                    a += wv[0]*p0.x + wv[1]*p0.y + wv[2]*p0.z + wv[3]*p0.w;
                    a += wv[4]*p1.x + wv[5]*p1.y + wv[6]*p1.z + wv[7]*p1.w;
                    acc[k] = a;
                }
            }
            float part = 0.f;
            const int row = side ? (b*256 + r0 - 256 + r) : (b*256 + r0 + r);
            float* dst = side ? (ws + 262144 + row*128) : (ws + row*128);
            #pragma unroll
            for (int k = 0; k < 8; ++k) {
                const int g = q + 16*k;
                part = fmaf(0.505f * Wa2[g], acc[k], part);
                dst[g] = acc[k];
            }
            part += __shfl_xor(part, 1);
            part += __shfl_xor(part, 2);
            part += __shfl_xor(part, 4);
            part += __shfl_xor(part, 8);
            if (q == 0) {
                if (!side) ws[FB + 2320 + row] = part;          // C1PO
                else       ws[FB + 4368 + row] = part;          // C2
            }
        }
    } else {
        const int b = blockIdx.x - 256;
        float* f = (float*)Wa1s;     // alias LDS
        float* state = f;            // 64
        float* hvec  = f + 64;       // 64
        float* gl    = f + 128;      // 256
        float* hn_s  = f + 384;      // 64
        float* t0a   = f + 448;      // 128
        float* t1a   = f + 576;      // 128
        float* s2s   = f + 704;      // 128
        float* red   = f + 832;      // 256

        {
            const int d = t & 63, q = t >> 6;
            const float* p = ope + b*16512 + (1 + q*64)*64 + d;
            float s = 0.f;
            #pragma unroll 8
            for (int r = 0; r < 64; ++r) s += p[r*64];
            red[t] = s;
        }
        __syncthreads();
        if (t < 64)       state[t]   = (red[t] + red[t+64] + red[t+128] + red[t+192]) * (1.f/256.f);
        else if (t < 128) hvec[t-64] = hin[b*64 + (t-64)];
        __syncthreads();

        {
            float g = b_ih[t] + b_hh[t];
            const float4* wi = (const float4*)(W_ih + t*64);
            const float4* wh = (const float4*)(W_hh + t*64);
            #pragma unroll
            for (int k = 0; k < 16; ++k)
                g += dot4(wi[k], *(const float4*)&state[k*4])
                   + dot4(wh[k], *(const float4*)&hvec[k*4]);
            gl[t] = g;
        }
        __syncthreads();

        if (t < 64) {
            const float ig = gl[t], fg = gl[64+t], gg = gl[128+t], og = gl[192+t];
            const float c  = cin[b*64 + t];
            const float si = 1.f/(1.f + expf(-ig));
            const float sf = 1.f/(1.f + expf(-fg));
            const float so = 1.f/(1.f + expf(-og));
            const float cn = sf*c + si*tanhf(gg);
            const float hn = so*tanhf(cn);
            ws[FB + 1288 + b*64 + t] = hn;
            ws[FB + 1800 + b*64 + t] = cn;
            hn_s[t] = hn;
        }
        __syncthreads();

        if (t < 128) {
            float a = bv0[t];
            const float4* w = (const float4*)(Wv0 + t*64);
            #pragma unroll
            for (int k = 0; k < 16; ++k) a += dot4(w[k], *(const float4*)&hn_s[k*4]);
            t0a[t] = a;
        }
        __syncthreads();
        if (t < 128) {
            float a = bv1[t];
            const float4* w = (const float4*)(Wv1 + t*128);
            #pragma unroll
            for (int k = 0; k < 32; ++k) a += dot4(w[k], *(const float4*)&t0a[k*4]);
            a = (a >= 0.f) ? a : 0.01f*a;
            t1a[t] = a * Wv2[t];
            float s2 = ba0[t];
            const float4* w0 = (const float4*)(Wa0 + t*192);
            #pragma unroll
            for (int k = 0; k < 16; ++k) s2 += dot4(w0[k], *(const float4*)&hn_s[k*4]);
            s2s[t] = s2;
        }
        __syncthreads();
        if (t < 128) {
            float sv = ba1[t];
            const float4* w = (const float4*)(Wa1 + t*128);
            #pragma unroll
            for (int k = 0; k < 32; ++k) sv += dot4(w[k], *(const float4*)&s2s[k*4]);
            ws[FB + SOFF + b*128 + t] = sv;
            red[t] = 0.505f * Wa2[t] * sv;
        }
        __syncthreads();
        if (t < 64) {
            float c = red[t] + red[t + 64];
            float v = t1a[t] + t1a[t + 64];
            c += __shfl_xor(c, 32); v += __shfl_xor(v, 32);
            c += __shfl_xor(c, 16); v += __shfl_xor(v, 16);
            c += __shfl_xor(c, 8);  v += __shfl_xor(v, 8);
            c += __shfl_xor(c, 4);  v += __shfl_xor(v, 4);
            c += __shfl_xor(c, 2);  v += __shfl_xor(v, 2);
            c += __shfl_xor(c, 1);  v += __shfl_xor(v, 1);
            if (t == 0) {
                ws[FB + C1S + b]  = c + ba2[0];
                ws[FB + 1280 + b] = v + bv2[0];
            }
        }
    }

    // ======================= DEVICE BARRIER =======================
    __syncthreads();
    if (t == 0) {
        int it = 0;
        while (aload(&wsi[BFLAG]) != MAGIC && it < 5000000) ++it;   // wait init
        __threadfence();                                            // release phase-1 writes
        __hip_atomic_fetch_add(&wsi[BCNT], 1, __ATOMIC_ACQ_REL, __HIP_MEMORY_SCOPE_AGENT);
        it = 0;
        while (aload(&wsi[BCNT]) < NBLK && it < 5000000) ++it;      // wait all arrivals
    }
    __syncthreads();

    // ======================= PHASE 2 =======================
    // A[b][o][i] = C1PO + C1S + C2 + sum_g 0.495*Wa2[g]*|PO + S + Y|
    for (int u = blockIdx.x; u < 512; u += NBLK) {
        const int b = u >> 6;
        const int o0 = (u & 63) * 4;

        float acc[4] = {0.f, 0.f, 0.f, 0.f};
        #pragma unroll
        for (int gc = 0; gc < 8; ++gc) {
            float syv[16], wv[16];
            {
                const float* yr = ws + 262144 + (b*256 + t)*128 + gc*16;
                const float* sr = ws + FB + SOFF + b*128 + gc*16;    // uniform
                const float* wr = Wa2 + gc*16;                       // uniform
                #pragma unroll
                for (int k = 0; k < 4; ++k) {
                    const float4 y4 = *(const float4*)(yr + k*4);
                    const float4 s4 = *(const float4*)(sr + k*4);
                    const float4 w4 = *(const float4*)(wr + k*4);
                    syv[k*4+0] = y4.x + s4.x; syv[k*4+1] = y4.y + s4.y;
                    syv[k*4+2] = y4.z + s4.z; syv[k*4+3] = y4.w + s4.w;
                    wv[k*4+0] = 0.495f*w4.x; wv[k*4+1] = 0.495f*w4.y;
                    wv[k*4+2] = 0.495f*w4.z; wv[k*4+3] = 0.495f*w4.w;
                }
            }
            #pragma unroll
            for (int o = 0; o < 4; ++o) {
                const float* xr = ws + (b*256 + o0 + o)*128 + gc*16;   // uniform
                float a = acc[o];
                #pragma unroll
                for (int k = 0; k < 4; ++k) {
                    const float4 x4 = *(const float4*)(xr + k*4);
                    a = fmaf(wv[k*4+0], fabsf(x4.x + syv[k*4+0]), a);
                    a = fmaf(wv[k*4+1], fabsf(x4.y + syv[k*4+1]), a);
                    a = fmaf(wv[k*4+2], fabsf(x4.z + syv[k*4+2]), a);
                    a = fmaf(wv[k*4+3], fabsf(x4.w + syv[k*4+3]), a);
                }
                acc[o] = a;
            }
        }
        const float c2  = ws[FB + 4368 + b*256 + t];
        const float c1s = ws[FB + C1S + b];
        #pragma unroll
        for (int o = 0; o < 4; ++o)
            out[8 + b*65536 + (o0 + o)*256 + t] =
                ws[FB + 2320 + b*256 + o0 + o] + c1s + c2 + acc[o];
    }

    if (blockIdx.x == 0) {
        if (t < 8) out[t] = ws[FB + 1280 + t];              // V fp32
        #pragma unroll
        for (int j = t; j < 512; j += 256) {
            out[524296 + j] = ws[FB + 1288 + j];            // hn fp32
            out[524808 + j] = ws[FB + 1800 + j];            // cn fp32
        }
    }
}

// ============================================================================
extern "C" void kernel_launch(void* const* d_in, const int* in_sizes, int n_in,
                              void* d_out, int out_size, void* d_ws, size_t ws_size,
                              hipStream_t stream) {
    float* ws = (float*)d_ws;
    float* out = (float*)d_out;                 // output is fp32

    k_all<<<dim3(NBLK), dim3(256), 0, stream>>>(
        (const float*)d_in[0], (const float*)d_in[1],
        (const float*)d_in[2], (const float*)d_in[3],
        (const float*)d_in[4], (const float*)d_in[5],
        (const float*)d_in[6], (const float*)d_in[7],
        (const float*)d_in[8], (const float*)d_in[9],
        (const float*)d_in[10], (const float*)d_in[11],
        (const float*)d_in[12], (const float*)d_in[13],
        (const float*)d_in[14], (const float*)d_in[15],
        (const float*)d_in[16], (const float*)d_in[17],
        (const float*)d_in[18], (const float*)d_in[19], ws, out);
}

// Round 13
// 123.868 us; speedup vs baseline: 1.4620x; 1.4620x over previous
//
#include <hip/hip_runtime.h>
#include <hip/hip_bf16.h>
#include <math.h>

typedef unsigned short u16;

// ---- ws layout (float offsets), FB = 524288 ----
// [0, 262144)        : PO[b][o][g] fp32
// [262144, 524288)   : Y[b][i][g] fp32
// FB+1280 .. +1288   : V fp32                  (k12 LSTM blocks)
// FB+1288 .. +1800   : hn fp32
// FB+1800 .. +2312   : cn fp32
// FB+2320 .. +4368   : C1PO[b][o] = sum_g wa'*PO
// FB+4368 .. +6416   : C2[b][i]   = sum_g wa'*Y
// FB+26896.. +27920  : S[b][g] = s2.Wa1 + ba1
// FB+27920.. +27928  : C1S[b] = sum_g wa'*S + ba2
#define FB    524288
#define SOFF  26896
#define C1S   27920

__device__ __forceinline__ u16 f2b(float x) { __hip_bfloat16 b = __float2bfloat16(x); return *(u16*)&b; }
__device__ __forceinline__ void cvt8(const uint4 u, float* f) {
    f[0] = __uint_as_float(u.x << 16); f[1] = __uint_as_float(u.x & 0xFFFF0000u);
    f[2] = __uint_as_float(u.y << 16); f[3] = __uint_as_float(u.y & 0xFFFF0000u);
    f[4] = __uint_as_float(u.z << 16); f[5] = __uint_as_float(u.z & 0xFFFF0000u);
    f[6] = __uint_as_float(u.w << 16); f[7] = __uint_as_float(u.w & 0xFFFF0000u);
}
__device__ __forceinline__ float dot4(const float4 a, const float4 b) {
    return a.x*b.x + a.y*b.y + a.z*b.z + a.w*b.w;
}

// ============================================================================
// K12: blocks 0..255 = PO/Y tiles (+C1PO/C2 reduces, self-staged weights);
//      blocks 256..263 = mean + LSTM + V head + S[b][g] + C1S[b].
// grid(264), block(256). Depends only on inputs.
// ============================================================================
__global__ __launch_bounds__(256) void k12_main(
    const float* __restrict__ ope, const float* __restrict__ ins,
    const float* __restrict__ hin, const float* __restrict__ cin,
    const float* __restrict__ W_ih, const float* __restrict__ W_hh,
    const float* __restrict__ b_ih, const float* __restrict__ b_hh,
    const float* __restrict__ Wv0, const float* __restrict__ bv0,
    const float* __restrict__ Wv1, const float* __restrict__ bv1,
    const float* __restrict__ Wv2, const float* __restrict__ bv2,
    const float* __restrict__ Wa0, const float* __restrict__ ba0,
    const float* __restrict__ Wa1, const float* __restrict__ ba1,
    const float* __restrict__ Wa2, const float* __restrict__ ba2,
    float* __restrict__ ws)
{
    __shared__ __align__(16) u16 Wa1s[128*136];
    __shared__ __align__(16) u16 Wsel[128*72];
    __shared__ __align__(16) u16 inrows[16*72];
    __shared__ __align__(16) float P[16*132];
    const int t = threadIdx.x;

    if (blockIdx.x < 256) {
        // ---------------- PO / Y tile ----------------
        const int b = blockIdx.x >> 5;
        const int r0 = (blockIdx.x & 31) * 16;
        const int side = (r0 >= 256) ? 1 : 0;

        // stage Wa1 fp32 -> LDS bf16 [128][136]
        #pragma unroll
        for (int k = 0; k < 16; ++k) {
            const int e4 = t + k*256;
            const int g = e4 >> 5, hq = (e4 & 31) * 4;
            const float4 w = *(const float4*)(Wa1 + g*128 + hq);
            ushort4 u; u.x = f2b(w.x); u.y = f2b(w.y); u.z = f2b(w.z); u.w = f2b(w.w);
            *(ushort4*)&Wa1s[g*136 + hq] = u;
        }
        // stage Wo/Wi fp32 -> LDS bf16 [128][72]
        #pragma unroll
        for (int k = 0; k < 8; ++k) {
            const int e4 = t + k*256;
            const int h = e4 >> 4, dq = (e4 & 15) * 4;
            const float4 w = *(const float4*)(Wa0 + h*192 + 64 + side*64 + dq);
            ushort4 u; u.x = f2b(w.x); u.y = f2b(w.y); u.z = f2b(w.z); u.w = f2b(w.w);
            *(ushort4*)&Wsel[h*72 + dq] = u;
        }
        // stage 16 input rows -> LDS bf16 [16][72]
        {
            const int r = t >> 4, dq = (t & 15) * 4;
            const float* src = side
                ? (ins + b*16384 + (r0 - 256 + r)*64 + dq)
                : (ope + b*16512 + (1 + r0 + r)*64 + dq);
            const float4 w = *(const float4*)src;
            ushort4 u; u.x = f2b(w.x); u.y = f2b(w.y); u.z = f2b(w.z); u.w = f2b(w.w);
            *(ushort4*)&inrows[r*72 + dq] = u;
        }
        __syncthreads();

        const int r = t >> 4;
        const int q = t & 15;

        // P[r][h] = inrow[r] . Wsel[h]
        {
            float acc[8] = {0.f,0.f,0.f,0.f,0.f,0.f,0.f,0.f};
            #pragma unroll
            for (int d8 = 0; d8 < 64; d8 += 8) {
                float iv[8];
                cvt8(*(const uint4*)&inrows[r*72 + d8], iv);
                #pragma unroll
                for (int k = 0; k < 8; ++k) {
                    float wv[8];
                    cvt8(*(const uint4*)&Wsel[(q + 16*k)*72 + d8], wv);
                    #pragma unroll
                    for (int j = 0; j < 8; ++j) acc[k] += wv[j] * iv[j];
                }
            }
            #pragma unroll
            for (int k = 0; k < 8; ++k) P[r*132 + q + 16*k] = acc[k];
        }
        __syncthreads();

        // out[r][g] = P[r] . Wa1[g]; C-reduce over g with wa' = 0.505*Wa2
        {
            float acc[8] = {0.f,0.f,0.f,0.f,0.f,0.f,0.f,0.f};
            #pragma unroll
            for (int h8 = 0; h8 < 128; h8 += 8) {
                const float4 p0 = *(const float4*)&P[r*132 + h8];
                const float4 p1 = *(const float4*)&P[r*132 + h8 + 4];
                #pragma unroll
                for (int k = 0; k < 8; ++k) {
                    float wv[8];
                    cvt8(*(const uint4*)&Wa1s[(q + 16*k)*136 + h8], wv);
                    float a = acc[k];
                    a += wv[0]*p0.x + wv[1]*p0.y + wv[2]*p0.z + wv[3]*p0.w;
                    a += wv[4]*p1.x + wv[5]*p1.y + wv[6]*p1.z + wv[7]*p1.w;
                    acc[k] = a;
                }
            }
            float part = 0.f;
            const int row = side ? (b*256 + r0 - 256 + r) : (b*256 + r0 + r);
            float* dst = side ? (ws + 262144 + row*128) : (ws + row*128);
            #pragma unroll
            for (int k = 0; k < 8; ++k) {
                const int g = q + 16*k;
                part = fmaf(0.505f * Wa2[g], acc[k], part);
                dst[g] = acc[k];
            }
            part += __shfl_xor(part, 1);
            part += __shfl_xor(part, 2);
            part += __shfl_xor(part, 4);
            part += __shfl_xor(part, 8);
            if (q == 0) {
                if (!side) ws[FB + 2320 + row] = part;          // C1PO
                else       ws[FB + 4368 + row] = part;          // C2
            }
        }
    } else {
        // ---------------- mean + LSTM + V head + S + C1S (block b) ----------
        const int b = blockIdx.x - 256;
        float* f = (float*)Wa1s;     // alias LDS
        float* state = f;            // 64
        float* hvec  = f + 64;       // 64
        float* gl    = f + 128;      // 256
        float* hn_s  = f + 384;      // 64
        float* t0a   = f + 448;      // 128
        float* t1a   = f + 576;      // 128
        float* s2s   = f + 704;      // 128
        float* red   = f + 832;      // 256

        // mean over rows 1..256 of ope[b], directly (hidden under PO blocks)
        {
            const int d = t & 63, q = t >> 6;
            const float* p = ope + b*16512 + (1 + q*64)*64 + d;
            float s = 0.f;
            #pragma unroll 8
            for (int r = 0; r < 64; ++r) s += p[r*64];
            red[t] = s;
        }
        __syncthreads();
        if (t < 64)       state[t]   = (red[t] + red[t+64] + red[t+128] + red[t+192]) * (1.f/256.f);
        else if (t < 128) hvec[t-64] = hin[b*64 + (t-64)];
        __syncthreads();

        {
            float g = b_ih[t] + b_hh[t];
            const float4* wi = (const float4*)(W_ih + t*64);
            const float4* wh = (const float4*)(W_hh + t*64);
            #pragma unroll
            for (int k = 0; k < 16; ++k)
                g += dot4(wi[k], *(const float4*)&state[k*4])
                   + dot4(wh[k], *(const float4*)&hvec[k*4]);
            gl[t] = g;
        }
        __syncthreads();

        if (t < 64) {
            const float ig = gl[t], fg = gl[64+t], gg = gl[128+t], og = gl[192+t];
            const float c  = cin[b*64 + t];
            const float si = 1.f/(1.f + expf(-ig));
            const float sf = 1.f/(1.f + expf(-fg));
            const float so = 1.f/(1.f + expf(-og));
            const float cn = sf*c + si*tanhf(gg);
            const float hn = so*tanhf(cn);
            ws[FB + 1288 + b*64 + t] = hn;
            ws[FB + 1800 + b*64 + t] = cn;
            hn_s[t] = hn;
        }
        __syncthreads();

        if (t < 128) {
            float a = bv0[t];
            const float4* w = (const float4*)(Wv0 + t*64);
            #pragma unroll
            for (int k = 0; k < 16; ++k) a += dot4(w[k], *(const float4*)&hn_s[k*4]);
            t0a[t] = a;
        }
        __syncthreads();
        if (t < 128) {
            float a = bv1[t];
            const float4* w = (const float4*)(Wv1 + t*128);
            #pragma unroll
            for (int k = 0; k < 32; ++k) a += dot4(w[k], *(const float4*)&t0a[k*4]);
            a = (a >= 0.f) ? a : 0.01f*a;
            t1a[t] = a * Wv2[t];
            float s2 = ba0[t];
            const float4* w0 = (const float4*)(Wa0 + t*192);
            #pragma unroll
            for (int k = 0; k < 16; ++k) s2 += dot4(w0[k], *(const float4*)&hn_s[k*4]);
            s2s[t] = s2;
        }
        __syncthreads();
        if (t < 128) {
            // S[b][g] = s2 . Wa1[g] + ba1[g]   (fp32 Wa1)
            float sv = ba1[t];
            const float4* w = (const float4*)(Wa1 + t*128);
            #pragma unroll
            for (int k = 0; k < 32; ++k) sv += dot4(w[k], *(const float4*)&s2s[k*4]);
            ws[FB + SOFF + b*128 + t] = sv;
            red[t] = 0.505f * Wa2[t] * sv;          // wa' * S
        }
        __syncthreads();
        if (t < 64) {
            float c = red[t] + red[t + 64];
            float v = t1a[t] + t1a[t + 64];
            c += __shfl_xor(c, 32); v += __shfl_xor(v, 32);
            c += __shfl_xor(c, 16); v += __shfl_xor(v, 16);
            c += __shfl_xor(c, 8);  v += __shfl_xor(v, 8);
            c += __shfl_xor(c, 4);  v += __shfl_xor(v, 4);
            c += __shfl_xor(c, 2);  v += __shfl_xor(v, 2);
            c += __shfl_xor(c, 1);  v += __shfl_xor(v, 1);
            if (t == 0) {
                ws[FB + C1S + b]  = c + ba2[0];
                ws[FB + 1280 + b] = v + bv2[0];
            }
        }
    }
}

// ============================================================================
// K3: A[b][o][i] = C1PO[b,o] + C1S[b] + C2[b,i] + sum_g wb'[g]*|PO + S + Y|,
// wb' = 0.495*Wa2. grid(512), block(256). Block 0 emits V/hn/cn last.
// ============================================================================
__global__ __launch_bounds__(256) void k3_adv(const float* __restrict__ ws,
                                              const float* __restrict__ Wa2,
                                              float* __restrict__ out)
{
    const int t = threadIdx.x;
    const int b = blockIdx.x >> 6;
    const int o0 = (blockIdx.x & 63) * 4;

    float acc[4] = {0.f, 0.f, 0.f, 0.f};
    #pragma unroll
    for (int gc = 0; gc < 8; ++gc) {              // 16 g per chunk
        float syv[16], wv[16];
        {
            const float* yr = ws + 262144 + (b*256 + t)*128 + gc*16;
            const float* sr = ws + FB + SOFF + b*128 + gc*16;    // uniform
            const float* wr = Wa2 + gc*16;                       // uniform
            #pragma unroll
            for (int k = 0; k < 4; ++k) {
                const float4 y4 = *(const float4*)(yr + k*4);
                const float4 s4 = *(const float4*)(sr + k*4);
                const float4 w4 = *(const float4*)(wr + k*4);
                syv[k*4+0] = y4.x + s4.x; syv[k*4+1] = y4.y + s4.y;
                syv[k*4+2] = y4.z + s4.z; syv[k*4+3] = y4.w + s4.w;
                wv[k*4+0] = 0.495f*w4.x; wv[k*4+1] = 0.495f*w4.y;
                wv[k*4+2] = 0.495f*w4.z; wv[k*4+3] = 0.495f*w4.w;
            }
        }
        #pragma unroll
        for (int o = 0; o < 4; ++o) {
            const float* xr = ws + (b*256 + o0 + o)*128 + gc*16;   // uniform
            float a = acc[o];
            #pragma unroll
            for (int k = 0; k < 4; ++k) {
                const float4 x4 = *(const float4*)(xr + k*4);
                a = fmaf(wv[k*4+0], fabsf(x4.x + syv[k*4+0]), a);
                a = fmaf(wv[k*4+1], fabsf(x4.y + syv[k*4+1]), a);
                a = fmaf(wv[k*4+2], fabsf(x4.z + syv[k*4+2]), a);
                a = fmaf(wv[k*4+3], fabsf(x4.w + syv[k*4+3]), a);
            }
            acc[o] = a;
        }
    }
    const float c2  = ws[FB + 4368 + b*256 + t];
    const float c1s = ws[FB + C1S + b];
    #pragma unroll
    for (int o = 0; o < 4; ++o)
        out[8 + b*65536 + (o0 + o)*256 + t] =
            ws[FB + 2320 + b*256 + o0 + o] + c1s + c2 + acc[o];

    if (blockIdx.x == 0) {
        if (t < 8) out[t] = ws[FB + 1280 + t];              // V fp32
        #pragma unroll
        for (int j = t; j < 512; j += 256) {
            out[524296 + j] = ws[FB + 1288 + j];            // hn fp32
            out[524808 + j] = ws[FB + 1800 + j];            // cn fp32
        }
    }
}

// ============================================================================
extern "C" void kernel_launch(void* const* d_in, const int* in_sizes, int n_in,
                              void* d_out, int out_size, void* d_ws, size_t ws_size,
                              hipStream_t stream) {
    float* ws = (float*)d_ws;
    float* out = (float*)d_out;                 // output is fp32

    k12_main<<<dim3(264), dim3(256), 0, stream>>>(
        (const float*)d_in[0], (const float*)d_in[1],
        (const float*)d_in[2], (const float*)d_in[3],
        (const float*)d_in[4], (const float*)d_in[5],
        (const float*)d_in[6], (const float*)d_in[7],
        (const float*)d_in[8], (const float*)d_in[9],
        (const float*)d_in[10], (const float*)d_in[11],
        (const float*)d_in[12], (const float*)d_in[13],
        (const float*)d_in[14], (const float*)d_in[15],
        (const float*)d_in[16], (const float*)d_in[17],
        (const float*)d_in[18], (const float*)d_in[19], ws);
    k3_adv  <<<dim3(512), dim3(256), 0, stream>>>(ws, (const float*)d_in[18], out);
}